// Round 1
// baseline (382.336 us; speedup 1.0000x reference)
//
#include <hip/hip_runtime.h>
#include <hip/hip_bf16.h>

#define TT 1000
#define CC 3
#define HH 64
#define WW 64
#define HW (HH * WW)           // 4096
#define CHW (CC * HW)          // 12288
#define NCHUNK 50
#define CLEN 20                // NCHUNK*CLEN == TT

// out[0:CHW] = x[0:CHW]  (xT slice; d_out is poisoned before every call)
__global__ __launch_bounds__(256) void copy_xT_kernel(const float* __restrict__ x,
                                                      float* __restrict__ out) {
    int i = blockIdx.x * blockDim.x + threadIdx.x;
    if (i < CHW) out[i] = x[i];
}

// et_updated[t,c,h,w] = et_coeff[t] * (conv3x3(xin[t])[c,h,w] + temb[tarr[t], c])
// one thread per (t,h,w), computes all 3 output channels
__global__ __launch_bounds__(256) void conv_kernel(const float* __restrict__ xin,
                                                   const float* __restrict__ conv_w,
                                                   const float* __restrict__ temb,
                                                   const int* __restrict__ tarr,
                                                   const float* __restrict__ et_coeff,
                                                   float* __restrict__ A) {
    int idx = blockIdx.x * blockDim.x + threadIdx.x;   // over TT*HW
    if (idx >= TT * HW) return;
    int w = idx & (WW - 1);
    int h = (idx >> 6) & (HH - 1);
    int t = idx >> 12;

    // stage the 81 weights in LDS once per block
    __shared__ float sw[CC * CC * 9];
    if (threadIdx.x < CC * CC * 9) sw[threadIdx.x] = conv_w[threadIdx.x];
    __syncthreads();

    const float* xs = xin + (size_t)t * CHW;
    float acc0 = 0.f, acc1 = 0.f, acc2 = 0.f;
    #pragma unroll
    for (int ci = 0; ci < CC; ++ci) {
        const float* xc = xs + ci * HW;
        #pragma unroll
        for (int kh = 0; kh < 3; ++kh) {
            int hh = h + kh - 1;
            if (hh < 0 || hh >= HH) continue;
            #pragma unroll
            for (int kw = 0; kw < 3; ++kw) {
                int wcol = w + kw - 1;
                if (wcol < 0 || wcol >= WW) continue;
                float v = xc[hh * WW + wcol];
                acc0 += v * sw[((0 * CC + ci) * 3 + kh) * 3 + kw];
                acc1 += v * sw[((1 * CC + ci) * 3 + kh) * 3 + kw];
                acc2 += v * sw[((2 * CC + ci) * 3 + kh) * 3 + kw];
            }
        }
    }
    int trow = tarr[t];
    float ec = et_coeff[t];
    float* o = A + (size_t)t * CHW + h * WW + w;
    o[0 * HW] = ec * (acc0 + temb[trow * CC + 0]);
    o[1 * HW] = ec * (acc1 + temb[trow * CC + 1]);
    o[2 * HW] = ec * (acc2 + temb[trow * CC + 2]);
}

// S[ch*CHW + pos] = sum over the 20 t's in chunk ch of A[t*CHW + pos]
__global__ __launch_bounds__(256) void chunk_sum_kernel(const float* __restrict__ A,
                                                        float* __restrict__ S) {
    int idx = blockIdx.x * blockDim.x + threadIdx.x;   // NCHUNK*CHW
    if (idx >= NCHUNK * CHW) return;
    int pos = idx % CHW;
    int ch = idx / CHW;
    const float* p = A + (size_t)ch * CLEN * CHW + pos;
    float acc = 0.f;
    #pragma unroll
    for (int i = 0; i < CLEN; ++i) acc += p[(size_t)i * CHW];
    S[idx] = acc;
}

// in-place exclusive scan over the NCHUNK chunk totals, per position
__global__ __launch_bounds__(256) void offset_scan_kernel(float* __restrict__ S) {
    int pos = blockIdx.x * blockDim.x + threadIdx.x;
    if (pos >= CHW) return;
    float run = 0.f;
    #pragma unroll
    for (int ch = 0; ch < NCHUNK; ++ch) {
        float v = S[ch * CHW + pos];
        S[ch * CHW + pos] = run;
        run += v;
    }
}

// out[(t+1)*CHW + pos] = alpha_ratio[t]*xT[pos] + et_prevsum_coeff[t]*prefix(t,pos)
__global__ __launch_bounds__(256) void final_kernel(const float* __restrict__ A,
                                                    const float* __restrict__ S,
                                                    const float* __restrict__ xT,
                                                    const float* __restrict__ ar,
                                                    const float* __restrict__ epc,
                                                    float* __restrict__ out) {
    int idx = blockIdx.x * blockDim.x + threadIdx.x;   // NCHUNK*CHW
    if (idx >= NCHUNK * CHW) return;
    int pos = idx % CHW;
    int ch = idx / CHW;
    float acc = S[idx];
    float xv = xT[pos];
    const float* p = A + (size_t)ch * CLEN * CHW + pos;
    float* q = out + (size_t)(ch * CLEN + 1) * CHW + pos;
    #pragma unroll
    for (int i = 0; i < CLEN; ++i) {
        int t = ch * CLEN + i;
        acc += p[(size_t)i * CHW];
        q[(size_t)i * CHW] = ar[t] * xv + epc[t] * acc;
    }
}

extern "C" void kernel_launch(void* const* d_in, const int* in_sizes, int n_in,
                              void* d_out, int out_size, void* d_ws, size_t ws_size,
                              hipStream_t stream) {
    const float* x    = (const float*)d_in[0];   // (T+1, C, H, W)
    const int*   tarr = (const int*)  d_in[1];   // (T,)
    const float* ar   = (const float*)d_in[2];   // (T,1,1,1)
    const float* ec   = (const float*)d_in[3];   // (T,1,1,1)
    const float* epc  = (const float*)d_in[4];   // (T,1,1,1)
    const float* cw   = (const float*)d_in[5];   // (C,C,3,3)
    const float* temb = (const float*)d_in[6];   // (T,C)
    float* out = (float*)d_out;                  // (T+1, C, H, W)

    float* A = (float*)d_ws;                     // TT*CHW floats (49.15 MB)
    float* S = A + (size_t)TT * CHW;             // NCHUNK*CHW floats (2.46 MB)

    copy_xT_kernel<<<(CHW + 255) / 256, 256, 0, stream>>>(x, out);

    for (int it = 0; it < 3; ++it) {
        const float* xin = (it == 0) ? x : out;  // slices 0..T-1 of previous xt
        conv_kernel<<<(TT * HW + 255) / 256, 256, 0, stream>>>(xin, cw, temb, tarr, ec, A);
        chunk_sum_kernel<<<(NCHUNK * CHW + 255) / 256, 256, 0, stream>>>(A, S);
        offset_scan_kernel<<<(CHW + 255) / 256, 256, 0, stream>>>(S);
        final_kernel<<<(NCHUNK * CHW + 255) / 256, 256, 0, stream>>>(A, S, x, ar, epc, out);
    }
}